// Round 18
// baseline (130.551 us; speedup 1.0000x reference)
//
#include <hip/hip_runtime.h>
#include <hip/hip_bf16.h>

// KAN layer: B=32768, D=256, K=10 — MFMA + split-D EIGHTHS, 2-kernel version.
// Round 18: (a) kan_prep ELIMINATED — each kan_main block computes its own
// eighth's weights directly into LDS (no cross-block deps; index math verbatim
// from the r15 prep, e-base removed); kan_epi computes cs redundantly
// per-block. 3 dispatches -> 2. (b) DIAGNOSTIC replication: main x2 (rep 1
// writes dummy P), epi x16 (reps 1..15 write dummy out region) so BOTH rise
// above the ~40us harness fill dispatches and expose counters; decomposition
// fixed+gaps = total - main_disp - epi_disp.
//
// slot->kk map (verified r7/r9): main step (d, k=v in 0..7) with d = qb+hi*4+J;
// tail step d = qb+hi*4+(v>>1), k = 8+(v&1). A and B use the same map.
//
// LDS per main block (floats, per eighth):
//   [0,640)     WB  f32 [32 dl][20]: (w1s,b1s)*LOG2E2 pairs k=0..7 (16 used)
//   [640,768)   TWB f32 [2 ql][4 hi][8 v][2]: tail (w,b)*LOG2E2
//   [768,2176)  WM  bf16 [32 dl][11 m][8 k] (ushort idx 1536+dl*88+m*8+k)
//   [2176,2496) WTL bf16 [2 ql][4 hi][10 m][8 v] (ushort 4352+(ql*4+hi)*80+m*8+v)
// ws (floats): [20480 + rep*3145728 + e*393216) P f32 [2 rep][8 e][32768 row][12]
//   epi dummy out at [6400000, 6432768)

#define LOG2E2 2.885390081777927f   // 2*log2(e)

#if __has_builtin(__builtin_amdgcn_exp2f)
#define EXP2F(x) __builtin_amdgcn_exp2f(x)
#else
#define EXP2F(x) __expf((x) * 0.6931471805599453f)
#endif
#if __has_builtin(__builtin_amdgcn_rcpf)
#define RCPF(x) __builtin_amdgcn_rcpf(x)
#else
#define RCPF(x) (1.0f / (x))
#endif
// tanh(a) with t = 2*log2(e)*a: 1 - 2/(2^t+1)
#define TANHS(DST, T) do { float _e = EXP2F(T); DST = fmaf(-2.0f, RCPF(_e + 1.0f), 1.0f); } while (0)

typedef __attribute__((ext_vector_type(8))) short short8v;
typedef __attribute__((ext_vector_type(4))) float f32x4;
typedef __attribute__((ext_vector_type(4))) unsigned uint4v;

__device__ __forceinline__ unsigned cvt_pk_bf16(float lo, float hi) {
    unsigned r;
    asm("v_cvt_pk_bf16_f32 %0, %1, %2" : "=v"(r) : "v"(lo), "v"(hi));
    return r;
}

#define PACK8(DST) { \
    uint4v _uu; \
    _uu.x = cvt_pk_bf16(h0, h1); \
    _uu.y = cvt_pk_bf16(h2, h3); \
    _uu.z = cvt_pk_bf16(h4, h5); \
    _uu.w = cvt_pk_bf16(h6, h7); \
    DST = __builtin_bit_cast(short8v, _uu); \
}

__device__ __forceinline__ ushort f2bf(float f) {
    union { float f; unsigned u; } a; a.f = f;
    unsigned u = a.u;
    u += 0x7FFF + ((u >> 16) & 1);
    return (ushort)(u >> 16);
}

// 8 tanh for one tile from scalar X and (w,b) quads p0..p3, packed into DST
#define HTILE_S(DST, X) { \
    float h0, h1, h2, h3, h4, h5, h6, h7; \
    TANHS(h0, fmaf(X, p0.x, p0.y)); TANHS(h1, fmaf(X, p0.z, p0.w)); \
    TANHS(h2, fmaf(X, p1.x, p1.y)); TANHS(h3, fmaf(X, p1.z, p1.w)); \
    TANHS(h4, fmaf(X, p2.x, p2.y)); TANHS(h5, fmaf(X, p2.z, p2.w)); \
    TANHS(h6, fmaf(X, p3.x, p3.y)); TANHS(h7, fmaf(X, p3.z, p3.w)); \
    PACK8(DST) \
}
// tail variant: components of float4 X map to v-pairs
#define HTILE_T(DST, X) { \
    float h0, h1, h2, h3, h4, h5, h6, h7; \
    TANHS(h0, fmaf(X.x, p0.x, p0.y)); TANHS(h1, fmaf(X.x, p0.z, p0.w)); \
    TANHS(h2, fmaf(X.y, p1.x, p1.y)); TANHS(h3, fmaf(X.y, p1.z, p1.w)); \
    TANHS(h4, fmaf(X.z, p2.x, p2.y)); TANHS(h5, fmaf(X.z, p2.z, p2.w)); \
    TANHS(h6, fmaf(X.w, p3.x, p3.y)); TANHS(h7, fmaf(X.w, p3.z, p3.w)); \
    PACK8(DST) \
}

// one main step: d = qb+hi4+J (local, <32), k=0..7; both tiles share LDS reads
#define MAINSTEP2(J, XA, XB) { \
    const int d_ = qb + hi4 + (J); \
    const float* wb_ = ldsF + d_ * 20; \
    const float4 p0 = *(const float4*)(wb_); \
    const float4 p1 = *(const float4*)(wb_ + 4); \
    const float4 p2 = *(const float4*)(wb_ + 8); \
    const float4 p3 = *(const float4*)(wb_ + 12); \
    short8v av0_, av1_; \
    HTILE_S(av0_, XA) \
    HTILE_S(av1_, XB) \
    const short8v bf_ = *(const short8v*)(ldsU + 1536 + d_ * 88 + meff8); \
    acc0 = __builtin_amdgcn_mfma_f32_16x16x32_bf16(av0_, bf_, acc0, 0, 0, 0); \
    acc1 = __builtin_amdgcn_mfma_f32_16x16x32_bf16(av1_, bf_, acc1, 0, 0, 0); \
}

// tail step for local group q (0..1): d = qb+hi4+(v>>1), k = 8+(v&1)
#define TAILSTEP2 { \
    const float* tw_ = ldsF + 640 + q * 64 + hi16; \
    const float4 p0 = *(const float4*)(tw_); \
    const float4 p1 = *(const float4*)(tw_ + 4); \
    const float4 p2 = *(const float4*)(tw_ + 8); \
    const float4 p3 = *(const float4*)(tw_ + 12); \
    short8v av0_, av1_; \
    HTILE_T(av0_, xq0) \
    HTILE_T(av1_, xq1) \
    const short8v bf_ = *(const short8v*)(ldsU + 4352 + q * 320 + hi80 + meff8); \
    acc0 = __builtin_amdgcn_mfma_f32_16x16x32_bf16(av0_, bf_, acc0, 0, 0, 0); \
    acc1 = __builtin_amdgcn_mfma_f32_16x16x32_bf16(av1_, bf_, acc1, 0, 0, 0); \
}

__global__ __launch_bounds__(256, 8)
void kan_main(const float* __restrict__ x, float* __restrict__ ws,
              const float* __restrict__ w1, const float* __restrict__ b1,
              const float* __restrict__ w2, const float* __restrict__ wo1) {
    __shared__ float4 ldsRaw[624];             // 9,984 B -> 8 blocks/CU
    float* ldsF = (float*)ldsRaw;
    ushort* ldsUx = (ushort*)ldsRaw;
    const ushort* ldsU = (const ushort*)ldsRaw;

    const int t = threadIdx.x;
    const int bid = blockIdx.x;
    const int rep = bid >> 11;                 // 0 = real, 1 = diagnostic
    const int inner = bid & 2047;
    const int rb = inner & 255;                // row-block (128 rows)
    const int e  = inner >> 8;                 // d-eighth (0..7)
    const int d0 = e * 32;

    // ---- prologue: compute this eighth's weights directly into LDS ----
    for (int item = t; item < 3840; item += 256) {
        if (item < 3200) {
            // Wf[d,k,m] = sum_j w2[d,k,j]*wo1[d*10+j, m]
            int m = item % 10;
            int k = (item / 10) % 10;
            int dl = item / 100;
            int d = d0 + dl;
            const float* w2p = w2 + d * 100 + k * 10;
            const float* wop = wo1 + d * 100 + m;
            float v = 0.f;
            #pragma unroll
            for (int j = 0; j < 10; ++j) v = fmaf(w2p[j], wop[j * 10], v);
            ushort hv = f2bf(v);
            if (k < 8) {
                ldsUx[1536 + (dl * 11 + m) * 8 + k] = hv;
            } else {
                int ql = dl >> 4, hi2 = (dl >> 2) & 3, vv = ((dl & 3) << 1) | (k - 8);
                ldsUx[4352 + ((ql * 4 + hi2) * 10 + m) * 8 + vv] = hv;
            }
        } else if (item < 3712) {
            int id = item - 3200;
            int dl = id >> 4, r = id & 15, v = r >> 1;
            ldsF[dl * 20 + r] = ((r & 1) ? b1 : w1)[(d0 + dl) * 10 + v] * LOG2E2;
        } else {
            int id = item - 3712;
            int which = id & 1, slot = id >> 1;
            int v = slot & 7, hi2 = (slot >> 3) & 3, ql = slot >> 5;
            int d = d0 + ql * 16 + hi2 * 4 + (v >> 1);
            int k = 8 + (v & 1);
            ldsF[640 + slot * 2 + which] = ((which) ? b1 : w1)[d * 10 + k] * LOG2E2;
        }
    }
    __syncthreads();

    const int lane = t & 63;
    const int wave = t >> 6;
    const int m = lane & 15;                   // A row within tile AND C/D col
    const int hi = lane >> 4;
    const int hi4 = hi * 4, hi16 = hi * 16, hi80 = hi * 80;
    const int meff8 = ((m < 10) ? m : 0) * 8;
    const int rows0 = rb * 128 + wave * 32;
    const float* xr0 = x + (size_t)(rows0 + m) * 256 + e * 32;
    const float* xr1 = xr0 + 16 * 256;

    f32x4 acc0 = {0.f, 0.f, 0.f, 0.f};
    f32x4 acc1 = {0.f, 0.f, 0.f, 0.f};

    #pragma unroll
    for (int q = 0; q < 2; ++q) {
        const int qb = q * 16;
        const float4 xq0 = *(const float4*)(xr0 + qb + hi4);
        const float4 xq1 = *(const float4*)(xr1 + qb + hi4);
        MAINSTEP2(0, xq0.x, xq1.x)
        MAINSTEP2(1, xq0.y, xq1.y)
        MAINSTEP2(2, xq0.z, xq1.z)
        MAINSTEP2(3, xq0.w, xq1.w)
        TAILSTEP2
    }

    // store partials: acc[r] = row rows0(+16)+hi4+r, col m
    if (m < 10) {
        float* P = ws + 20480 + (size_t)rep * 3145728 + (size_t)e * 393216;
        float* pa = P + (size_t)(rows0 + hi4) * 12 + m;
        pa[0] = acc0[0]; pa[12] = acc0[1]; pa[24] = acc0[2]; pa[36] = acc0[3];
        float* pb = P + (size_t)(rows0 + 16 + hi4) * 12 + m;
        pb[0] = acc1[0]; pb[12] = acc1[1]; pb[24] = acc1[2]; pb[36] = acc1[3];
    }
}

#define EPIM(AV, M) { \
    float t_ = fmaf(LOG2E2, (AV), csS[M]); \
    float u_; TANHS(u_, t_); \
    o = fmaf(u_, wo2[M], o); \
}

__global__ void kan_epi(const float* __restrict__ ws, const float* __restrict__ b2,
                        const float* __restrict__ wo1, const float* __restrict__ bo1,
                        const float* __restrict__ wo2, const float* __restrict__ bo2,
                        float* __restrict__ out, float* __restrict__ wsd) {
    __shared__ float red[40];
    __shared__ float csS[10];
    const int tt = threadIdx.x;
    const int bid = blockIdx.x;
    const int rep = bid >> 7;                  // 0 = real, 1..15 diagnostic
    const int rbid = bid & 127;

    // cs[m] = bo1[m] + sum_r b2[r]*wo1[r*10+m], computed redundantly per block
    {
        float c0 = 0.f, c1 = 0.f, c2 = 0.f, c3 = 0.f, c4 = 0.f;
        float c5 = 0.f, c6 = 0.f, c7 = 0.f, c8 = 0.f, c9 = 0.f;
        #pragma unroll
        for (int i = 0; i < 10; ++i) {
            int r = tt * 10 + i;
            float bv = b2[r];
            const float* wp = wo1 + r * 10;
            c0 = fmaf(bv, wp[0], c0); c1 = fmaf(bv, wp[1], c1);
            c2 = fmaf(bv, wp[2], c2); c3 = fmaf(bv, wp[3], c3);
            c4 = fmaf(bv, wp[4], c4); c5 = fmaf(bv, wp[5], c5);
            c6 = fmaf(bv, wp[6], c6); c7 = fmaf(bv, wp[7], c7);
            c8 = fmaf(bv, wp[8], c8); c9 = fmaf(bv, wp[9], c9);
        }
        #pragma unroll
        for (int s = 1; s < 64; s <<= 1) {
            c0 += __shfl_xor(c0, s); c1 += __shfl_xor(c1, s);
            c2 += __shfl_xor(c2, s); c3 += __shfl_xor(c3, s);
            c4 += __shfl_xor(c4, s); c5 += __shfl_xor(c5, s);
            c6 += __shfl_xor(c6, s); c7 += __shfl_xor(c7, s);
            c8 += __shfl_xor(c8, s); c9 += __shfl_xor(c9, s);
        }
        int lane = tt & 63, w = tt >> 6;
        if (lane == 0) {
            red[w * 10 + 0] = c0; red[w * 10 + 1] = c1; red[w * 10 + 2] = c2;
            red[w * 10 + 3] = c3; red[w * 10 + 4] = c4; red[w * 10 + 5] = c5;
            red[w * 10 + 6] = c6; red[w * 10 + 7] = c7; red[w * 10 + 8] = c8;
            red[w * 10 + 9] = c9;
        }
        __syncthreads();
        if (tt < 10) {
            float v = red[tt] + red[10 + tt] + red[20 + tt] + red[30 + tt];
            csS[tt] = LOG2E2 * (v + bo1[tt]);
        }
        __syncthreads();
    }

    const int row = rbid * 256 + tt;
    const float* Pr = ws + 20480 + (size_t)row * 12;
    float s0 = 0.f, s1 = 0.f, s2 = 0.f, s3 = 0.f, s4 = 0.f;
    float s5 = 0.f, s6 = 0.f, s7 = 0.f, s8 = 0.f, s9 = 0.f;
    #pragma unroll
    for (int ee = 0; ee < 8; ++ee) {
        const float4* P = (const float4*)(Pr + (size_t)ee * 393216);
        float4 a0 = P[0], a1 = P[1], a2 = P[2];
        s0 += a0.x; s1 += a0.y; s2 += a0.z; s3 += a0.w;
        s4 += a1.x; s5 += a1.y; s6 += a1.z; s7 += a1.w;
        s8 += a2.x; s9 += a2.y;
    }
    float o = bo2[0];
    EPIM(s0, 0) EPIM(s1, 1) EPIM(s2, 2) EPIM(s3, 3) EPIM(s4, 4)
    EPIM(s5, 5) EPIM(s6, 6) EPIM(s7, 7) EPIM(s8, 8) EPIM(s9, 9)
    if (rep == 0) out[row] = o;
    else          wsd[row] = o;    // diagnostic replicas: identical values, benign
}

extern "C" void kernel_launch(void* const* d_in, const int* in_sizes, int n_in,
                              void* d_out, int out_size, void* d_ws, size_t ws_size,
                              hipStream_t stream) {
    const float* x   = (const float*)d_in[0];
    const float* w1  = (const float*)d_in[1];
    const float* b1  = (const float*)d_in[2];
    const float* w2  = (const float*)d_in[3];
    const float* b2  = (const float*)d_in[4];
    const float* wo1 = (const float*)d_in[5];
    const float* bo1 = (const float*)d_in[6];
    const float* wo2 = (const float*)d_in[7];
    const float* bo2 = (const float*)d_in[8];
    float* out = (float*)d_out;
    float* ws  = (float*)d_ws;

    hipLaunchKernelGGL(kan_main, dim3(4096), dim3(256), 0, stream,
                       x, ws, w1, b1, w2, wo1);
    hipLaunchKernelGGL(kan_epi, dim3(2048), dim3(256), 0, stream,
                       ws, b2, wo1, bo1, wo2, bo2, out, ws + 6400000);
}

// Round 20
// 35.382 us; speedup vs baseline: 3.6898x; 3.6898x over previous
//
#include <hip/hip_runtime.h>
#include <hip/hip_bf16.h>

// KAN layer: B=32768, D=256, K=10 — MFMA + split-D EIGHTHS, fast prep.
// Round 20: identical resubmit of r19 (container died before the kernel ran).
// r18 decomposition: main-compute 23us, epi 2us, gaps 3.5us, PREP ~17us
// (121 blocks = 0.5/CU, 20 scalar loads per Wf item -> latency bound).
// New prep: 257 blocks — one per d staging w2[d]/wo1[d] (100+100 floats) into
// LDS via coalesced float4, 100 threads x 10 LDS-FMAs for Wf, threads
// 100..119 emit WB/TWB; block 256 computes cs (parallel reduce).
// kan_main and kan_epi are byte-identical to r15 (passing, main ~23us).
//
// slot->kk map (verified r7/r9): main step (d, k=v in 0..7) with d = qb+hi*4+J;
// tail step d = qb+hi*4+(v>>1), k = 8+(v&1). A and B use the same map.
//
// ws layout (floats):
//   per eighth e (at e*2496, total [0,19968)):
//     [0,640)     WB  f32 [32 dl][20]: (w1s,b1s) pairs k=0..7 (16 used)
//     [640,768)   TWB f32 [2 ql][4 hi][8 v][2]: tail (w,b)
//     [768,2176)  WM  bf16 [32 dl][11 m][8 k] (ushort idx e*4992+1536+dl*88+m*8+k)
//     [2176,2496) WTL bf16 [2 ql][4 hi][10 m][8 v] (ushort e*4992+4352+(ql*4+hi)*80+m*8+v)
//   [19968,19978) CS f32: cs[m] = LOG2E2*(bo1[m]+sum b2*wo1)
//   [20480 + e*393216 ...) P f32 [8 e][32768 row][12]

#define LOG2E2 2.885390081777927f   // 2*log2(e)

#if __has_builtin(__builtin_amdgcn_exp2f)
#define EXP2F(x) __builtin_amdgcn_exp2f(x)
#else
#define EXP2F(x) __expf((x) * 0.6931471805599453f)
#endif
#if __has_builtin(__builtin_amdgcn_rcpf)
#define RCPF(x) __builtin_amdgcn_rcpf(x)
#else
#define RCPF(x) (1.0f / (x))
#endif
// tanh(a) with t = 2*log2(e)*a: 1 - 2/(2^t+1)
#define TANHS(DST, T) do { float _e = EXP2F(T); DST = fmaf(-2.0f, RCPF(_e + 1.0f), 1.0f); } while (0)

typedef __attribute__((ext_vector_type(8))) short short8v;
typedef __attribute__((ext_vector_type(4))) float f32x4;
typedef __attribute__((ext_vector_type(4))) unsigned uint4v;

__device__ __forceinline__ unsigned cvt_pk_bf16(float lo, float hi) {
    unsigned r;
    asm("v_cvt_pk_bf16_f32 %0, %1, %2" : "=v"(r) : "v"(lo), "v"(hi));
    return r;
}

#define PACK8(DST) { \
    uint4v _uu; \
    _uu.x = cvt_pk_bf16(h0, h1); \
    _uu.y = cvt_pk_bf16(h2, h3); \
    _uu.z = cvt_pk_bf16(h4, h5); \
    _uu.w = cvt_pk_bf16(h6, h7); \
    DST = __builtin_bit_cast(short8v, _uu); \
}

__device__ __forceinline__ ushort f2bf(float f) {
    union { float f; unsigned u; } a; a.f = f;
    unsigned u = a.u;
    u += 0x7FFF + ((u >> 16) & 1);
    return (ushort)(u >> 16);
}

__global__ __launch_bounds__(256)
void kan_prep(const float* __restrict__ w1, const float* __restrict__ b1,
              const float* __restrict__ w2, const float* __restrict__ b2,
              const float* __restrict__ wo1, const float* __restrict__ bo1,
              float* __restrict__ ws) {
    __shared__ float w2d[100];
    __shared__ float wo1d[100];
    __shared__ float red[40];
    float* wsF = ws;
    ushort* wsU = (ushort*)ws;
    const int tt = threadIdx.x;

    if (blockIdx.x == 256) {
        // cs[10], parallel over 256 threads (r18-proven)
        float c0 = 0.f, c1 = 0.f, c2 = 0.f, c3 = 0.f, c4 = 0.f;
        float c5 = 0.f, c6 = 0.f, c7 = 0.f, c8 = 0.f, c9 = 0.f;
        #pragma unroll
        for (int it = 0; it < 10; ++it) {
            int r = tt + it * 256;
            float bv = b2[r];
            const float* wp = wo1 + r * 10;
            c0 = fmaf(bv, wp[0], c0); c1 = fmaf(bv, wp[1], c1);
            c2 = fmaf(bv, wp[2], c2); c3 = fmaf(bv, wp[3], c3);
            c4 = fmaf(bv, wp[4], c4); c5 = fmaf(bv, wp[5], c5);
            c6 = fmaf(bv, wp[6], c6); c7 = fmaf(bv, wp[7], c7);
            c8 = fmaf(bv, wp[8], c8); c9 = fmaf(bv, wp[9], c9);
        }
        #pragma unroll
        for (int s = 1; s < 64; s <<= 1) {
            c0 += __shfl_xor(c0, s); c1 += __shfl_xor(c1, s);
            c2 += __shfl_xor(c2, s); c3 += __shfl_xor(c3, s);
            c4 += __shfl_xor(c4, s); c5 += __shfl_xor(c5, s);
            c6 += __shfl_xor(c6, s); c7 += __shfl_xor(c7, s);
            c8 += __shfl_xor(c8, s); c9 += __shfl_xor(c9, s);
        }
        int lane = tt & 63, w = tt >> 6;
        if (lane == 0) {
            red[w * 10 + 0] = c0; red[w * 10 + 1] = c1; red[w * 10 + 2] = c2;
            red[w * 10 + 3] = c3; red[w * 10 + 4] = c4; red[w * 10 + 5] = c5;
            red[w * 10 + 6] = c6; red[w * 10 + 7] = c7; red[w * 10 + 8] = c8;
            red[w * 10 + 9] = c9;
        }
        __syncthreads();
        if (tt < 10) {
            float v = red[tt] + red[10 + tt] + red[20 + tt] + red[30 + tt];
            wsF[19968 + tt] = LOG2E2 * (v + bo1[tt]);
        }
        return;
    }

    // one block per d: coalesced stage of w2[d,*,*] and wo1[d*10+*, *]
    const int d = blockIdx.x;
    if (tt < 25)       ((float4*)w2d)[tt]       = ((const float4*)(w2 + d * 100))[tt];
    else if (tt < 50)  ((float4*)wo1d)[tt - 25] = ((const float4*)(wo1 + d * 100))[tt - 25];
    __syncthreads();

    const int e = d >> 5, dl = d & 31;
    if (tt < 100) {
        // Wf[d,k,m] = sum_j w2d[k*10+j] * wo1d[j*10+m]
        int k = tt / 10, m = tt - k * 10;
        float v = 0.f;
        #pragma unroll
        for (int j = 0; j < 10; ++j) v = fmaf(w2d[k * 10 + j], wo1d[j * 10 + m], v);
        ushort hv = f2bf(v);
        if (k < 8) {
            wsU[e * 4992 + 1536 + (dl * 11 + m) * 8 + k] = hv;
        } else {
            int ql = (d >> 4) & 1, hi = (d >> 2) & 3, vv = ((d & 3) << 1) | (k - 8);
            wsU[e * 4992 + 4352 + ((ql * 4 + hi) * 10 + m) * 8 + vv] = hv;
        }
    } else if (tt < 116) {
        // WB: r = 2v+which, v=0..7
        int r = tt - 100;
        int v = r >> 1;
        wsF[e * 2496 + dl * 20 + r] = ((r & 1) ? b1 : w1)[d * 10 + v] * LOG2E2;
    } else if (tt < 120) {
        // TWB: k = 8+(id>>1), which = id&1; v = ((d&3)<<1)|(k-8)
        int id = tt - 116;
        int which = id & 1, kk = 8 + (id >> 1);
        int ql = (d >> 4) & 1, hi = (d >> 2) & 3;
        int v = ((d & 3) << 1) | (kk - 8);
        int slot = (ql * 4 + hi) * 8 + v;
        wsF[e * 2496 + 640 + slot * 2 + which] = ((which) ? b1 : w1)[d * 10 + kk] * LOG2E2;
    }
}

// 8 tanh for one tile from scalar X and (w,b) quads p0..p3, packed into DST
#define HTILE_S(DST, X) { \
    float h0, h1, h2, h3, h4, h5, h6, h7; \
    TANHS(h0, fmaf(X, p0.x, p0.y)); TANHS(h1, fmaf(X, p0.z, p0.w)); \
    TANHS(h2, fmaf(X, p1.x, p1.y)); TANHS(h3, fmaf(X, p1.z, p1.w)); \
    TANHS(h4, fmaf(X, p2.x, p2.y)); TANHS(h5, fmaf(X, p2.z, p2.w)); \
    TANHS(h6, fmaf(X, p3.x, p3.y)); TANHS(h7, fmaf(X, p3.z, p3.w)); \
    PACK8(DST) \
}
// tail variant: components of float4 X map to v-pairs
#define HTILE_T(DST, X) { \
    float h0, h1, h2, h3, h4, h5, h6, h7; \
    TANHS(h0, fmaf(X.x, p0.x, p0.y)); TANHS(h1, fmaf(X.x, p0.z, p0.w)); \
    TANHS(h2, fmaf(X.y, p1.x, p1.y)); TANHS(h3, fmaf(X.y, p1.z, p1.w)); \
    TANHS(h4, fmaf(X.z, p2.x, p2.y)); TANHS(h5, fmaf(X.z, p2.z, p2.w)); \
    TANHS(h6, fmaf(X.w, p3.x, p3.y)); TANHS(h7, fmaf(X.w, p3.z, p3.w)); \
    PACK8(DST) \
}

// one main step: d = qb+hi4+J (local, <32), k=0..7; both tiles share LDS reads
#define MAINSTEP2(J, XA, XB) { \
    const int d_ = qb + hi4 + (J); \
    const float* wb_ = ldsF + d_ * 20; \
    const float4 p0 = *(const float4*)(wb_); \
    const float4 p1 = *(const float4*)(wb_ + 4); \
    const float4 p2 = *(const float4*)(wb_ + 8); \
    const float4 p3 = *(const float4*)(wb_ + 12); \
    short8v av0_, av1_; \
    HTILE_S(av0_, XA) \
    HTILE_S(av1_, XB) \
    const short8v bf_ = *(const short8v*)(ldsU + 1536 + d_ * 88 + meff8); \
    acc0 = __builtin_amdgcn_mfma_f32_16x16x32_bf16(av0_, bf_, acc0, 0, 0, 0); \
    acc1 = __builtin_amdgcn_mfma_f32_16x16x32_bf16(av1_, bf_, acc1, 0, 0, 0); \
}

// tail step for local group q (0..1): d = qb+hi4+(v>>1), k = 8+(v&1)
#define TAILSTEP2 { \
    const float* tw_ = ldsF + 640 + q * 64 + hi16; \
    const float4 p0 = *(const float4*)(tw_); \
    const float4 p1 = *(const float4*)(tw_ + 4); \
    const float4 p2 = *(const float4*)(tw_ + 8); \
    const float4 p3 = *(const float4*)(tw_ + 12); \
    short8v av0_, av1_; \
    HTILE_T(av0_, xq0) \
    HTILE_T(av1_, xq1) \
    const short8v bf_ = *(const short8v*)(ldsU + 4352 + q * 320 + hi80 + meff8); \
    acc0 = __builtin_amdgcn_mfma_f32_16x16x32_bf16(av0_, bf_, acc0, 0, 0, 0); \
    acc1 = __builtin_amdgcn_mfma_f32_16x16x32_bf16(av1_, bf_, acc1, 0, 0, 0); \
}

__global__ __launch_bounds__(256, 8)
void kan_main(const float* __restrict__ x, float* __restrict__ ws) {
    __shared__ float4 ldsRaw[624];             // 9,984 B -> 8 blocks/CU
    float* ldsF = (float*)ldsRaw;
    const ushort* ldsU = (const ushort*)ldsRaw;

    const int t = threadIdx.x;
    const int rb = blockIdx.x & 255;           // row-block (128 rows)
    const int e  = blockIdx.x >> 8;            // d-eighth (0..7)
    {
        const float4* src = (const float4*)(ws + e * 2496);
        for (int i = t; i < 624; i += 256) ldsRaw[i] = src[i];
    }
    __syncthreads();

    const int lane = t & 63;
    const int wave = t >> 6;
    const int m = lane & 15;                   // A row within tile AND C/D col
    const int hi = lane >> 4;
    const int hi4 = hi * 4, hi16 = hi * 16, hi80 = hi * 80;
    const int meff8 = ((m < 10) ? m : 0) * 8;
    const int rows0 = rb * 128 + wave * 32;
    const float* xr0 = x + (size_t)(rows0 + m) * 256 + e * 32;
    const float* xr1 = xr0 + 16 * 256;

    f32x4 acc0 = {0.f, 0.f, 0.f, 0.f};
    f32x4 acc1 = {0.f, 0.f, 0.f, 0.f};

    #pragma unroll
    for (int q = 0; q < 2; ++q) {
        const int qb = q * 16;
        const float4 xq0 = *(const float4*)(xr0 + qb + hi4);
        const float4 xq1 = *(const float4*)(xr1 + qb + hi4);
        MAINSTEP2(0, xq0.x, xq1.x)
        MAINSTEP2(1, xq0.y, xq1.y)
        MAINSTEP2(2, xq0.z, xq1.z)
        MAINSTEP2(3, xq0.w, xq1.w)
        TAILSTEP2
    }

    // store partials: acc[r] = row rows0(+16)+hi4+r, col m
    if (m < 10) {
        float* P = ws + 20480 + (size_t)e * 393216;
        float* pa = P + (size_t)(rows0 + hi4) * 12 + m;
        pa[0] = acc0[0]; pa[12] = acc0[1]; pa[24] = acc0[2]; pa[36] = acc0[3];
        float* pb = P + (size_t)(rows0 + 16 + hi4) * 12 + m;
        pb[0] = acc1[0]; pb[12] = acc1[1]; pb[24] = acc1[2]; pb[36] = acc1[3];
    }
}

#define EPIM(AV, M) { \
    float t_ = fmaf(LOG2E2, (AV), cs[M]); \
    float u_; TANHS(u_, t_); \
    o = fmaf(u_, wo2[M], o); \
}

__global__ void kan_epi(const float* __restrict__ ws, const float* __restrict__ wo2,
                        const float* __restrict__ bo2, float* __restrict__ out) {
    int row = blockIdx.x * 256 + threadIdx.x;
    float s0 = 0.f, s1 = 0.f, s2 = 0.f, s3 = 0.f, s4 = 0.f;
    float s5 = 0.f, s6 = 0.f, s7 = 0.f, s8 = 0.f, s9 = 0.f;
    #pragma unroll
    for (int e = 0; e < 8; ++e) {
        const float4* P = (const float4*)(ws + 20480 + (size_t)e * 393216 + (size_t)row * 12);
        float4 a0 = P[0], a1 = P[1], a2 = P[2];
        s0 += a0.x; s1 += a0.y; s2 += a0.z; s3 += a0.w;
        s4 += a1.x; s5 += a1.y; s6 += a1.z; s7 += a1.w;
        s8 += a2.x; s9 += a2.y;
    }
    const float* cs = ws + 19968;
    float o = bo2[0];
    EPIM(s0, 0) EPIM(s1, 1) EPIM(s2, 2) EPIM(s3, 3) EPIM(s4, 4)
    EPIM(s5, 5) EPIM(s6, 6) EPIM(s7, 7) EPIM(s8, 8) EPIM(s9, 9)
    out[row] = o;
}

extern "C" void kernel_launch(void* const* d_in, const int* in_sizes, int n_in,
                              void* d_out, int out_size, void* d_ws, size_t ws_size,
                              hipStream_t stream) {
    const float* x   = (const float*)d_in[0];
    const float* w1  = (const float*)d_in[1];
    const float* b1  = (const float*)d_in[2];
    const float* w2  = (const float*)d_in[3];
    const float* b2  = (const float*)d_in[4];
    const float* wo1 = (const float*)d_in[5];
    const float* bo1 = (const float*)d_in[6];
    const float* wo2 = (const float*)d_in[7];
    const float* bo2 = (const float*)d_in[8];
    float* out = (float*)d_out;
    float* ws  = (float*)d_ws;

    hipLaunchKernelGGL(kan_prep, dim3(257), dim3(256), 0, stream,
                       w1, b1, w2, b2, wo1, bo1, ws);
    hipLaunchKernelGGL(kan_main, dim3(2048), dim3(256), 0, stream, x, ws);
    hipLaunchKernelGGL(kan_epi, dim3(128), dim3(256), 0, stream,
                       ws, wo2, bo2, out);
}